// Round 4
// baseline (174.241 us; speedup 1.0000x reference)
//
#include <hip/hip_runtime.h>

// LengthRegulator: B=32, T=512, D=512, max_len=2048 (fixed by the problem).
// out[b, t, :] = x[b, searchsorted_right(cumsum(duration[b]), t), :] for
// t < sum(duration[b]), else zeros. mel_lengths[b] = max(sum, 1), stored as
// float at the tail of d_out (harness reads whole buffer as float32).
//
// Fused single-kernel design: each block owns (batch b, 128-frame chunk).
// Prologue: wave-shuffle inclusive scan of duration[b,:] (3 barriers, not 18),
// LDS binary search per frame, then stream 128 frames = 256 KiB of contiguous
// output with nontemporal float4 stores (output is never re-read; keep L2/L3
// for x reuse, which is ~3.5x re-read and L3-hot from the input restore).

#define BB      32
#define TT      512
#define DD      512
#define MAXLEN  2048
#define CHUNK   128                // frames per block
#define NCHUNK  (MAXLEN / CHUNK)   // 16 chunks per batch

// Native vector type: __builtin_nontemporal_store rejects HIP's float4 class.
typedef float f4 __attribute__((ext_vector_type(4)));

__global__ __launch_bounds__(512) void lr_fused_kernel(
    const int* __restrict__ dur, const f4* __restrict__ x,
    f4* __restrict__ out, float* __restrict__ mel_out) {
  __shared__ int s[TT];        // inclusive cumsum of duration[b,:]
  __shared__ int wsum[8];      // per-wave totals
  __shared__ int s_idx[CHUNK]; // phoneme index per frame (-1 = padding)

  const int b     = blockIdx.x >> 4;   // / NCHUNK
  const int chunk = blockIdx.x & (NCHUNK - 1);
  const int tid   = threadIdx.x;
  const int lane  = tid & 63;
  const int wave  = tid >> 6;          // 8 waves

  // --- inclusive scan of duration[b, :] -> s[] (3 barriers total) ---
  int v = dur[b * TT + tid];
#pragma unroll
  for (int off = 1; off < 64; off <<= 1) {
    int u = __shfl_up(v, off, 64);
    if (lane >= off) v += u;
  }
  if (lane == 63) wsum[wave] = v;
  __syncthreads();
  int add = 0;
#pragma unroll
  for (int w = 0; w < 7; ++w) add += (w < wave) ? wsum[w] : 0;
  s[tid] = v + add;
  __syncthreads();

  const int dsum = s[TT - 1];
  if (chunk == 0 && tid == 0) {
    mel_out[b] = (float)(dsum > 1 ? dsum : 1);
  }

  const int base = chunk * CHUNK;
  if (tid < CHUNK) {
    int t = base + tid;
    int r = -1;
    if (t < dsum) {
      // searchsorted right: first j with s[j] > t (LDS, 9 iterations)
      int lo = 0, hi = TT;
      while (lo < hi) {
        int mid = (lo + hi) >> 1;
        if (s[mid] <= t) lo = mid + 1; else hi = mid;
      }
      r = lo < (TT - 1) ? lo : (TT - 1);
    }
    s_idx[tid] = r;
  }
  __syncthreads();

  // Copy: 512 threads move 4 frames x 128 float4 per iteration, 32 iters.
  const int l4   = tid & 127;    // float4 lane within a frame row
  const int fsub = tid >> 7;     // 0..3: frame sub-slot per iteration
  const f4 zero = {0.f, 0.f, 0.f, 0.f};
#pragma unroll 8
  for (int it = 0; it < CHUNK / 4; ++it) {
    const int f = it * 4 + fsub;           // frame within chunk
    const int idx = s_idx[f];
    f4 val = zero;
    if (idx >= 0) {
      val = x[((size_t)b * TT + idx) * (DD / 4) + l4];
    }
    __builtin_nontemporal_store(
        val, &out[((size_t)b * MAXLEN + base + f) * (DD / 4) + l4]);
  }
}

extern "C" void kernel_launch(void* const* d_in, const int* in_sizes, int n_in,
                              void* d_out, int out_size, void* d_ws, size_t ws_size,
                              hipStream_t stream) {
  const float* x   = (const float*)d_in[0];
  const int*   dur = (const int*)d_in[1];
  // d_in[2] is max_len (=2048), static; hard-coded.
  float* out = (float*)d_out;
  float* mel_out = out + (size_t)BB * MAXLEN * DD;  // tail: 32 floats

  lr_fused_kernel<<<BB * NCHUNK, 512, 0, stream>>>(
      dur, (const f4*)x, (f4*)out, mel_out);
}